// Round 2
// baseline (79.806 us; speedup 1.0000x reference)
//
#include <hip/hip_runtime.h>
#include <hip/hip_bf16.h>
#include <stdint.h>

typedef unsigned short u16;
typedef unsigned int   u32;

#define N_ROWS 4096
#define DIM    512
#define NBLK   32          // N_ROWS / 128
#define MOD3   729         // 3^6
#define NLEV   6           // levels v = 0..5
#define NT     (DIM / 64)  // 8 K-tiles of 64

typedef __attribute__((ext_vector_type(8))) __bf16 bf16x8;
typedef __attribute__((ext_vector_type(4))) float  f32x4;

// ---- workspace layout (byte offsets) ----
#define WS_ZBF 0
#define WS_SQ  (N_ROWS * DIM * 2)
#define WS_R   (WS_SQ + N_ROWS * 4)
#define WS_ACC (WS_R + N_ROWS * 4)

// ---------------------------------------------------------------------------
// Prep: f32 -> bf16 (RNE), row sum-of-squares, residues mod 729, zero accums.
// ---------------------------------------------------------------------------
__global__ __launch_bounds__(64)
void prep_kernel(const float* __restrict__ z, const int* __restrict__ idx,
                 u16* __restrict__ zbf, float* __restrict__ sq,
                 int* __restrict__ rres, float* __restrict__ gsum,
                 u32* __restrict__ gcnt)
{
    const int row  = blockIdx.x;
    const int lane = threadIdx.x;
    const float4* zr = reinterpret_cast<const float4*>(z + (size_t)row * DIM) + lane * 2;
    float4 v0 = zr[0], v1 = zr[1];
    float f[8] = {v0.x, v0.y, v0.z, v0.w, v1.x, v1.y, v1.z, v1.w};
    float ss = 0.f;
    u16 u[8];
#pragma unroll
    for (int k = 0; k < 8; ++k) {
        ss += f[k] * f[k];
        u32 b = __builtin_bit_cast(u32, f[k]);
        u[k] = (u16)((b + 0x7FFFu + ((b >> 16) & 1u)) >> 16);   // RNE to bf16
    }
    *reinterpret_cast<uint4*>(zbf + (size_t)row * DIM + lane * 8) =
        *reinterpret_cast<const uint4*>(u);
#pragma unroll
    for (int off = 32; off > 0; off >>= 1) ss += __shfl_down(ss, off, 64);
    if (lane == 0) {
        sq[row]   = ss;
        rres[row] = idx[row] % MOD3;   // idx >= 0
    }
    if (row == 0 && lane < NLEV) { gsum[lane] = 0.f; gcnt[lane] = 0u; }
}

// ---------------------------------------------------------------------------
// Main: one block per upper-triangular 128x128 tile pair (bi <= bj).
// 2-phase pipeline (T3 minimum): STAGE(next buf) issued BEFORE compute(cur),
// one __syncthreads per K-tile (its implicit vmcnt(0) drains the prefetch
// whose latency was hidden under the current tile's ds_read+MFMA).
// LDS tiles XOR-swizzled (T2, rule #21): global_load_lds writes linearly, so
// the swizzle is applied by permuting the per-lane GLOBAL source column with
// the same involution used on the ds_read address:
//   store: lane l of chunk c covers (row = c*8 + (l>>3), colblk = (l&7)^(l>>3))
//   read : u16 index (row*64 + k) ^ ((row&7)<<3)
// This turns the 16-way row-column conflict into a free 2-way.
// Valuation: 6 magic-multiply divisibility tests (no LUT, no LDS byte reads).
// ---------------------------------------------------------------------------
__global__ __launch_bounds__(256)
void pair_kernel(const u16* __restrict__ zbf, const float* __restrict__ sq,
                 const int* __restrict__ rres, float* __restrict__ gsum,
                 u32* __restrict__ gcnt)
{
    __shared__ __align__(16) u16 As2[2][128 * 64];
    __shared__ __align__(16) u16 Bs2[2][128 * 64];
    __shared__ float sqI[128], sqJ[128];
    __shared__ int   rI[128], rJ[128];
    __shared__ float bsum[NLEV];
    __shared__ u32   bcnt[NLEV];

    const int tid  = threadIdx.x;
    const int lane = tid & 63;
    const int wave = tid >> 6;

    // linear block id -> (bi, bj), bi <= bj
    int t = blockIdx.x, bi = 0, rem = NBLK;
    while (t >= rem) { t -= rem; ++bi; rem = NBLK - bi; }
    const int bj = bi + t;
    const int I0 = bi * 128, J0 = bj * 128;

    if (tid < 128)      { sqI[tid] = sq[I0 + tid];       rI[tid] = rres[I0 + tid]; }
    else                { int s = tid - 128; sqJ[s] = sq[J0 + s]; rJ[s] = rres[J0 + s]; }
    if (tid < NLEV) { bsum[tid] = 0.f; bcnt[tid] = 0u; }

    const int wr = wave >> 1, wc = wave & 1;

    f32x4 acc[4][4];
#pragma unroll
    for (int m = 0; m < 4; ++m)
#pragma unroll
        for (int n = 0; n < 4; ++n) acc[m][n] = (f32x4){0.f, 0.f, 0.f, 0.f};

    const u16* Abase = zbf + (size_t)I0 * DIM;
    const u16* Bbase = zbf + (size_t)J0 * DIM;

    // staging geometry: 16 chunks/matrix of 1 KB (8 rows x 128 B); wave w owns
    // chunks 4w..4w+3. Source column pre-swizzled so linear LDS dest ends up
    // XOR-swizzled.
    const int rsub = lane >> 3;                     // 0..7 row within chunk
    const int bswz = (lane & 7) ^ rsub;             // swizzled 16B block
#define STAGE(buf, kt)                                                         \
    {                                                                          \
        const int colu = (kt) * 64 + bswz * 8;                                 \
        _Pragma("unroll")                                                      \
        for (int c4 = 0; c4 < 4; ++c4) {                                       \
            const int chunk = wave * 4 + c4;                                   \
            const int rowt  = chunk * 8 + rsub;                                \
            __builtin_amdgcn_global_load_lds(                                  \
                (const __attribute__((address_space(1))) u32*)                 \
                    (Abase + (size_t)rowt * DIM + colu),                       \
                (__attribute__((address_space(3))) u32*)&As2[buf][chunk * 512],\
                16, 0, 0);                                                     \
            __builtin_amdgcn_global_load_lds(                                  \
                (const __attribute__((address_space(1))) u32*)                 \
                    (Bbase + (size_t)rowt * DIM + colu),                       \
                (__attribute__((address_space(3))) u32*)&Bs2[buf][chunk * 512],\
                16, 0, 0);                                                     \
        }                                                                      \
    }

    STAGE(0, 0);
    __syncthreads();   // prologue drain (implicit vmcnt(0))

    int cur = 0;
    const int rA = lane & 15;
    for (int kt = 0; kt < NT; ++kt) {
        if (kt + 1 < NT) STAGE(cur ^ 1, kt + 1);   // prefetch next tile
#pragma unroll
        for (int ks = 0; ks < 2; ++ks) {
            const int k0 = ks * 32 + (lane >> 4) * 8;
            bf16x8 a[4], b[4];
#pragma unroll
            for (int m = 0; m < 4; ++m) {
                const int row = wr * 64 + m * 16 + rA;
                a[m] = *reinterpret_cast<const bf16x8*>(
                    &As2[cur][(row * 64 + k0) ^ ((row & 7) << 3)]);
            }
#pragma unroll
            for (int n = 0; n < 4; ++n) {
                const int row = wc * 64 + n * 16 + rA;
                b[n] = *reinterpret_cast<const bf16x8*>(
                    &Bs2[cur][(row * 64 + k0) ^ ((row & 7) << 3)]);
            }
#pragma unroll
            for (int m = 0; m < 4; ++m)
#pragma unroll
                for (int n = 0; n < 4; ++n)
                    acc[m][n] = __builtin_amdgcn_mfma_f32_16x16x32_bf16(a[m], b[n], acc[m][n], 0, 0, 0);
        }
        __syncthreads();   // implicit vmcnt(0): prefetch landed; reads done
        cur ^= 1;
    }
#undef STAGE

    // ---- fused epilogue ----
    float lsum[NLEV] = {0.f, 0.f, 0.f, 0.f, 0.f, 0.f};
    u32   lcnt[NLEV] = {0u, 0u, 0u, 0u, 0u, 0u};
    const int rbase = (lane >> 4) * 4;   // C/D: row = (lane>>4)*4 + q, col = lane&15
    const int cbase = lane & 15;
#pragma unroll
    for (int m = 0; m < 4; ++m) {
        const int il0 = wr * 64 + m * 16 + rbase;
#pragma unroll
        for (int n = 0; n < 4; ++n) {
            const int jl = wc * 64 + n * 16 + cbase;
            const int jg = J0 + jl;
            const float sqj = sqJ[jl];
            const int   rj  = rJ[jl];
#pragma unroll
            for (int q = 0; q < 4; ++q) {
                const int il = il0 + q;
                const int ig = I0 + il;
                if (jg > ig) {
                    const float dot  = acc[m][n][q];
                    float d2 = sqI[il] + sqj - 2.0f * dot;
                    d2 = fmaxf(d2, 0.f);
                    const float dist = sqrtf(d2);
                    int dm = rI[il] - rj;
                    dm += (dm >> 31) & MOD3;            // mod 729 into [0,729)
                    const u32 x = (u32)dm;
                    // v3 valuation capped at 6 via magic divisibility tests:
                    // 3^t | x  <=>  x * inv(3^t) <= floor((2^32-1)/3^t)
                    const int v =
                        (x * 2863311531u <= 1431655765u) +   // 3
                        (x *  954437177u <=  477218588u) +   // 9
                        (x * 1749801491u <=  159072862u) +   // 27
                        (x * 2014922929u <=   53024287u) +   // 81
                        (x * 3534952507u <=   17674762u) +   // 243
                        (x * 4041629033u <=    5891587u);    // 729 (x==0 -> 6)
                    float tv = 1.0f;
                    tv = (v == 1) ? (1.f / 3.f)   : tv;
                    tv = (v == 2) ? (1.f / 9.f)   : tv;
                    tv = (v == 3) ? (1.f / 27.f)  : tv;
                    tv = (v == 4) ? (1.f / 81.f)  : tv;
                    tv = (v == 5) ? (1.f / 243.f) : tv;
                    const float dd  = dist - tv;
                    const float sqd = dd * dd;
#pragma unroll
                    for (int vv = 0; vv < NLEV; ++vv) {
                        const bool hit = (v == vv);
                        lsum[vv] += hit ? sqd : 0.f;
                        lcnt[vv] += hit ? 1u : 0u;
                    }
                }
            }
        }
    }

    // wave shuffle reduce, then LDS, then global atomics
#pragma unroll
    for (int vv = 0; vv < NLEV; ++vv) {
        float s = lsum[vv];
        u32   c = lcnt[vv];
#pragma unroll
        for (int off = 32; off > 0; off >>= 1) {
            s += __shfl_xor(s, off, 64);
            c += __shfl_xor(c, off, 64);
        }
        if (lane == 0) { atomicAdd(&bsum[vv], s); atomicAdd(&bcnt[vv], c); }
    }
    __syncthreads();
    if (tid < NLEV) {
        atomicAdd(&gsum[tid], bsum[tid]);
        atomicAdd(&gcnt[tid], bcnt[tid]);
    }
}

// ---------------------------------------------------------------------------
__global__ void finalize_kernel(const float* __restrict__ gsum,
                                const u32* __restrict__ gcnt,
                                float* __restrict__ out)
{
    if (blockIdx.x == 0 && threadIdx.x == 0) {
        const float w[NLEV] = {1.f, 1.f / 2.f, 1.f / 3.f, 1.f / 4.f, 1.f / 5.f, 1.f / 6.f};
        float total = 0.f, lc = 0.f;
#pragma unroll
        for (int v = 0; v < NLEV; ++v) {
            const float cnt = (float)gcnt[v];
            const float mse = gsum[v] / fmaxf(cnt, 1.f);
            const bool  use = gcnt[v] >= 2u;
            total += use ? w[v] * mse : 0.f;
            lc    += use ? 1.f : 0.f;
        }
        out[0] = total / fmaxf(lc, 1.f);
    }
}

// ---------------------------------------------------------------------------
extern "C" void kernel_launch(void* const* d_in, const int* in_sizes, int n_in,
                              void* d_out, int out_size, void* d_ws, size_t ws_size,
                              hipStream_t stream)
{
    const float* z   = (const float*)d_in[0];
    const int*   idx = (const int*)d_in[1];
    char* ws = (char*)d_ws;
    u16*   zbf  = (u16*)(ws + WS_ZBF);
    float* sq   = (float*)(ws + WS_SQ);
    int*   rres = (int*)(ws + WS_R);
    float* gsum = (float*)(ws + WS_ACC);
    u32*   gcnt = (u32*)(ws + WS_ACC + NLEV * 4);
    float* out  = (float*)d_out;

    prep_kernel<<<N_ROWS, 64, 0, stream>>>(z, idx, zbf, sq, rres, gsum, gcnt);
    pair_kernel<<<NBLK * (NBLK + 1) / 2, 256, 0, stream>>>(zbf, sq, rres, gsum, gcnt);
    finalize_kernel<<<1, 64, 0, stream>>>(gsum, gcnt, out);
}

// Round 4
// 53.978 us; speedup vs baseline: 1.4785x; 1.4785x over previous
//
#include <hip/hip_runtime.h>
#include <hip/hip_bf16.h>
#include <stdint.h>

typedef unsigned short u16;
typedef unsigned int   u32;
typedef unsigned long long u64;

#define N_ROWS 4096
#define DIM    512
#define NBLK   32          // N_ROWS / 128
#define MOD3   729         // 3^6
#define NLEV   6           // levels v = 0..5
#define NT     (DIM / 64)  // 8 K-tiles of 64

typedef __attribute__((ext_vector_type(8))) __bf16 bf16x8;
typedef __attribute__((ext_vector_type(4))) float  f32x4;

// ---- workspace layout (byte offsets) ----
#define WS_ZBF 0
#define WS_SQ  (N_ROWS * DIM * 2)
#define WS_R   (WS_SQ + N_ROWS * 4)
#define WS_ACC (WS_R + N_ROWS * 4)

// ---------------------------------------------------------------------------
// Prep: f32 -> bf16 (RNE), row sum-of-squares, residues mod 729, zero accums.
// ---------------------------------------------------------------------------
__global__ __launch_bounds__(64)
void prep_kernel(const float* __restrict__ z, const int* __restrict__ idx,
                 u16* __restrict__ zbf, float* __restrict__ sq,
                 int* __restrict__ rres, float* __restrict__ gsum,
                 u32* __restrict__ gcnt)
{
    const int row  = blockIdx.x;
    const int lane = threadIdx.x;
    const float4* zr = reinterpret_cast<const float4*>(z + (size_t)row * DIM) + lane * 2;
    float4 v0 = zr[0], v1 = zr[1];
    float f[8] = {v0.x, v0.y, v0.z, v0.w, v1.x, v1.y, v1.z, v1.w};
    float ss = 0.f;
    u16 u[8];
#pragma unroll
    for (int k = 0; k < 8; ++k) {
        ss += f[k] * f[k];
        u32 b = __builtin_bit_cast(u32, f[k]);
        u[k] = (u16)((b + 0x7FFFu + ((b >> 16) & 1u)) >> 16);   // RNE to bf16
    }
    *reinterpret_cast<uint4*>(zbf + (size_t)row * DIM + lane * 8) =
        *reinterpret_cast<const uint4*>(u);
#pragma unroll
    for (int off = 32; off > 0; off >>= 1) ss += __shfl_down(ss, off, 64);
    if (lane == 0) {
        sq[row]   = ss;
        rres[row] = idx[row] % MOD3;   // idx >= 0
    }
    if (row == 0 && lane < NLEV) { gsum[lane] = 0.f; gcnt[lane] = 0u; }
}

// ---------------------------------------------------------------------------
// Epilogue body, specialized on DIAG (wave-uniform): off-diagonal tiles skip
// the jg>ig check entirely (bj>bi => always upper). Invalid / over-cap pairs
// fold to v=6, which matches no bucket -- fully straight-line, no exec churn.
// Counts for all 7 classes are packed into one u64 (6-bit fields, <=32 each).
// ---------------------------------------------------------------------------
template<bool DIAG>
__device__ __forceinline__ void epilogue_acc(
    const f32x4 (&acc)[4][2], const float* sqI, const float* sqJ,
    const int* rI, const int* rJ, int I0, int J0, int wr, int wc, int lane,
    float (&lsum)[NLEV], u64& pcnt)
{
    const int rbase = (lane >> 4) * 4;   // C/D: row = (lane>>4)*4 + q, col = lane&15
    const int cbase = lane & 15;
#pragma unroll
    for (int m = 0; m < 4; ++m) {
        const int il0 = wr * 64 + m * 16 + rbase;
#pragma unroll
        for (int n = 0; n < 2; ++n) {
            const int jl  = wc * 32 + n * 16 + cbase;
            const float sqj = sqJ[jl];
            const int   rj  = rJ[jl];
#pragma unroll
            for (int q = 0; q < 4; ++q) {
                const int il = il0 + q;
                const float dot = acc[m][n][q];
                float d2 = fmaxf(sqI[il] + sqj - 2.0f * dot, 0.f);
                const float dist = __builtin_amdgcn_sqrtf(d2);   // v_sqrt_f32
                int dm = rI[il] - rj;
                dm += (dm >> 31) & MOD3;            // mod 729 into [0,729)
                const u32 x = (u32)dm;
                // v3 valuation capped at 6: 3^t | x <=> x*inv(3^t) <= thr_t
                int v =
                    (x * 2863311531u <= 1431655765u) +   // 3
                    (x *  954437177u <=  477218588u) +   // 9
                    (x * 1749801491u <=  159072862u) +   // 27
                    (x * 2014922929u <=   53024287u) +   // 81
                    (x * 3534952507u <=   17674762u) +   // 243
                    (x * 4041629033u <=    5891587u);    // 729 (x==0 -> 6)
                if (DIAG) {
                    const int ig = I0 + il, jg = J0 + jl;
                    v = (jg > ig) ? v : 6;
                }
                float tv = 1.0f;
                tv = (v == 1) ? (1.f / 3.f)   : tv;
                tv = (v == 2) ? (1.f / 9.f)   : tv;
                tv = (v == 3) ? (1.f / 27.f)  : tv;
                tv = (v == 4) ? (1.f / 81.f)  : tv;
                tv = (v == 5) ? (1.f / 243.f) : tv;
                const float dd  = dist - tv;
                const float sqd = dd * dd;
#pragma unroll
                for (int vv = 0; vv < NLEV; ++vv)
                    lsum[vv] += (v == vv) ? sqd : 0.f;
                pcnt += 1ull << (6 * v);            // 6-bit field per class
            }
        }
    }
}

// ---------------------------------------------------------------------------
// Main: one block per upper-triangular 128x128 tile pair (bi <= bj).
// 512 threads = 8 waves in a 2x4 grid; each wave owns a 64x32 quadrant
// (acc[4][2] of 16x16x32 fragments) -> 16 waves/CU (2 blocks) = 4 waves/SIMD,
// doubling latency hiding vs the 4-wave version at identical traffic.
// 2-phase pipeline: STAGE(next) before compute(cur), one barrier per K-tile.
// LDS XOR-swizzled via pre-swizzled global source (round-2 verified, 0 confl).
// ---------------------------------------------------------------------------
__global__ __launch_bounds__(512, 4)
void pair_kernel(const u16* __restrict__ zbf, const float* __restrict__ sq,
                 const int* __restrict__ rres, float* __restrict__ gsum,
                 u32* __restrict__ gcnt)
{
    __shared__ __align__(16) u16 As2[2][128 * 64];
    __shared__ __align__(16) u16 Bs2[2][128 * 64];
    __shared__ float sqI[128], sqJ[128];
    __shared__ int   rI[128], rJ[128];
    __shared__ float bsum[NLEV];
    __shared__ u32   bcnt[NLEV];

    const int tid  = threadIdx.x;
    const int lane = tid & 63;
    const int wave = tid >> 6;

    // linear block id -> (bi, bj), bi <= bj
    int t = blockIdx.x, bi = 0, rem = NBLK;
    while (t >= rem) { t -= rem; ++bi; rem = NBLK - bi; }
    const int bj = bi + t;
    const int I0 = bi * 128, J0 = bj * 128;

    if (tid < 128)                     { sqI[tid] = sq[I0 + tid]; rI[tid] = rres[I0 + tid]; }
    else if (tid < 256)                { int s = tid - 128; sqJ[s] = sq[J0 + s]; rJ[s] = rres[J0 + s]; }
    if (tid < NLEV) { bsum[tid] = 0.f; bcnt[tid] = 0u; }

    const int wr = wave >> 2, wc = wave & 3;     // 2 x 4 wave grid

    f32x4 acc[4][2];
#pragma unroll
    for (int m = 0; m < 4; ++m)
#pragma unroll
        for (int n = 0; n < 2; ++n) acc[m][n] = (f32x4){0.f, 0.f, 0.f, 0.f};

    const u16* Abase = zbf + (size_t)I0 * DIM;
    const u16* Bbase = zbf + (size_t)J0 * DIM;

    // staging: 16 chunks/matrix of 1 KB (8 rows x 128 B); wave w owns chunks
    // {2w, 2w+1} of each matrix. Source column pre-swizzled (rule #21) so the
    // linear LDS dest ends up XOR-swizzled: read idx = (row*64+k) ^ ((row&7)<<3).
    const int rsub = lane >> 3;                     // 0..7 row within chunk
    const int bswz = (lane & 7) ^ rsub;             // swizzled 16B block
#define STAGE(buf, kt)                                                         \
    {                                                                          \
        const int colu = (kt) * 64 + bswz * 8;                                 \
        _Pragma("unroll")                                                      \
        for (int c2 = 0; c2 < 2; ++c2) {                                       \
            const int chunk = wave * 2 + c2;                                   \
            const int rowt  = chunk * 8 + rsub;                                \
            __builtin_amdgcn_global_load_lds(                                  \
                (const __attribute__((address_space(1))) u32*)                 \
                    (Abase + (size_t)rowt * DIM + colu),                       \
                (__attribute__((address_space(3))) u32*)&As2[buf][chunk * 512],\
                16, 0, 0);                                                     \
            __builtin_amdgcn_global_load_lds(                                  \
                (const __attribute__((address_space(1))) u32*)                 \
                    (Bbase + (size_t)rowt * DIM + colu),                       \
                (__attribute__((address_space(3))) u32*)&Bs2[buf][chunk * 512],\
                16, 0, 0);                                                     \
        }                                                                      \
    }

    STAGE(0, 0);
    __syncthreads();   // prologue drain (implicit vmcnt(0))

    int cur = 0;
    const int rA = lane & 15;
    for (int kt = 0; kt < NT; ++kt) {
        if (kt + 1 < NT) STAGE(cur ^ 1, kt + 1);   // prefetch next tile
#pragma unroll
        for (int ks = 0; ks < 2; ++ks) {
            const int k0 = ks * 32 + (lane >> 4) * 8;
            bf16x8 a[4], b[2];
#pragma unroll
            for (int m = 0; m < 4; ++m) {
                const int row = wr * 64 + m * 16 + rA;
                a[m] = *reinterpret_cast<const bf16x8*>(
                    &As2[cur][(row * 64 + k0) ^ ((row & 7) << 3)]);
            }
#pragma unroll
            for (int n = 0; n < 2; ++n) {
                const int row = wc * 32 + n * 16 + rA;
                b[n] = *reinterpret_cast<const bf16x8*>(
                    &Bs2[cur][(row * 64 + k0) ^ ((row & 7) << 3)]);
            }
#pragma unroll
            for (int m = 0; m < 4; ++m)
#pragma unroll
                for (int n = 0; n < 2; ++n)
                    acc[m][n] = __builtin_amdgcn_mfma_f32_16x16x32_bf16(a[m], b[n], acc[m][n], 0, 0, 0);
        }
        __syncthreads();   // implicit vmcnt(0): prefetch landed; reads done
        cur ^= 1;
    }
#undef STAGE

    // ---- fused epilogue ----
    float lsum[NLEV] = {0.f, 0.f, 0.f, 0.f, 0.f, 0.f};
    u64 pcnt = 0ull;
    if (bi == bj) epilogue_acc<true >(acc, sqI, sqJ, rI, rJ, I0, J0, wr, wc, lane, lsum, pcnt);
    else          epilogue_acc<false>(acc, sqI, sqJ, rI, rJ, I0, J0, wr, wc, lane, lsum, pcnt);

    // wave shuffle reduce, then LDS, then global atomics
#pragma unroll
    for (int vv = 0; vv < NLEV; ++vv) {
        float s = lsum[vv];
        u32   c = (u32)((pcnt >> (6 * vv)) & 63ull);
#pragma unroll
        for (int off = 32; off > 0; off >>= 1) {
            s += __shfl_xor(s, off, 64);
            c += __shfl_xor(c, off, 64);
        }
        if (lane == 0) { atomicAdd(&bsum[vv], s); atomicAdd(&bcnt[vv], c); }
    }
    __syncthreads();
    if (tid < NLEV) {
        atomicAdd(&gsum[tid], bsum[tid]);
        atomicAdd(&gcnt[tid], bcnt[tid]);
    }
}

// ---------------------------------------------------------------------------
__global__ void finalize_kernel(const float* __restrict__ gsum,
                                const u32* __restrict__ gcnt,
                                float* __restrict__ out)
{
    if (blockIdx.x == 0 && threadIdx.x == 0) {
        const float w[NLEV] = {1.f, 1.f / 2.f, 1.f / 3.f, 1.f / 4.f, 1.f / 5.f, 1.f / 6.f};
        float total = 0.f, lc = 0.f;
#pragma unroll
        for (int v = 0; v < NLEV; ++v) {
            const float cnt = (float)gcnt[v];
            const float mse = gsum[v] / fmaxf(cnt, 1.f);
            const bool  use = gcnt[v] >= 2u;
            total += use ? w[v] * mse : 0.f;
            lc    += use ? 1.f : 0.f;
        }
        out[0] = total / fmaxf(lc, 1.f);
    }
}

// ---------------------------------------------------------------------------
extern "C" void kernel_launch(void* const* d_in, const int* in_sizes, int n_in,
                              void* d_out, int out_size, void* d_ws, size_t ws_size,
                              hipStream_t stream)
{
    const float* z   = (const float*)d_in[0];
    const int*   idx = (const int*)d_in[1];
    char* ws = (char*)d_ws;
    u16*   zbf  = (u16*)(ws + WS_ZBF);
    float* sq   = (float*)(ws + WS_SQ);
    int*   rres = (int*)(ws + WS_R);
    float* gsum = (float*)(ws + WS_ACC);
    u32*   gcnt = (u32*)(ws + WS_ACC + NLEV * 4);
    float* out  = (float*)d_out;

    prep_kernel<<<N_ROWS, 64, 0, stream>>>(z, idx, zbf, sq, rres, gsum, gcnt);
    pair_kernel<<<NBLK * (NBLK + 1) / 2, 512, 0, stream>>>(zbf, sq, rres, gsum, gcnt);
    finalize_kernel<<<1, 64, 0, stream>>>(gsum, gcnt, out);
}

// Round 5
// 49.229 us; speedup vs baseline: 1.6211x; 1.0965x over previous
//
#include <hip/hip_runtime.h>
#include <hip/hip_bf16.h>
#include <stdint.h>

typedef unsigned short u16;
typedef unsigned int   u32;
typedef unsigned long long u64;

#define N_ROWS 4096
#define DIM    512
#define NBLK   32          // N_ROWS / 128
#define NPAIR  528         // NBLK*(NBLK+1)/2
#define MOD3   729         // 3^6
#define NLEV   6           // levels v = 0..5
#define NKS    16          // DIM / 32 k-steps

typedef __attribute__((ext_vector_type(8))) __bf16 bf16x8;
typedef __attribute__((ext_vector_type(4))) float  f32x4;

// ---- workspace layout (byte offsets) ----
// zpack: fragment-packed bf16. Block (R, s) for row-group R (16 rows) and
// k-step s (32 k) is 1 KB at ((R<<4)+s)*1024; lane L's 16 B at offset L*16
// holds elements row = R*16 + (L&15), k = s*32 + (L>>4)*8 + j  (j = 0..7)
// == exactly the mfma_16x16x32 A/B fragment for that (R, s).
#define WS_ZPK 0
#define WS_SQ  (N_ROWS * DIM * 2)
#define WS_R   (WS_SQ + N_ROWS * 4)
#define WS_ACC (WS_R + N_ROWS * 4)

// ---------------------------------------------------------------------------
// Prep: one wave per row. Coalesced f32 read, RNE->bf16, scatter-write the
// row's 8 fragment chunks into zpack (lane l holds k in [8l, 8l+8) ->
// zpack block (row>>4)*16 + (l>>2), byte (l&3)*256 + (row&15)*16).
// Also: row sum-of-squares, idx % 729, zero global accumulators.
// ---------------------------------------------------------------------------
__global__ __launch_bounds__(64)
void prep_kernel(const float* __restrict__ z, const int* __restrict__ idx,
                 u16* __restrict__ zpack, float* __restrict__ sq,
                 int* __restrict__ rres, float* __restrict__ gsum,
                 u32* __restrict__ gcnt)
{
    const int row  = blockIdx.x;
    const int lane = threadIdx.x;
    const float4* zr = reinterpret_cast<const float4*>(z + (size_t)row * DIM) + lane * 2;
    float4 v0 = zr[0], v1 = zr[1];
    float f[8] = {v0.x, v0.y, v0.z, v0.w, v1.x, v1.y, v1.z, v1.w};
    float ss = 0.f;
    u16 u[8];
#pragma unroll
    for (int k = 0; k < 8; ++k) {
        ss += f[k] * f[k];
        u32 b = __builtin_bit_cast(u32, f[k]);
        u[k] = (u16)((b + 0x7FFFu + ((b >> 16) & 1u)) >> 16);   // RNE to bf16
    }
    u16* dst = zpack + ((size_t)((row >> 4) * 16 + (lane >> 2)) * 512)
                     + ((lane & 3) * 16 + (row & 15)) * 8;
    *reinterpret_cast<uint4*>(dst) = *reinterpret_cast<const uint4*>(u);
#pragma unroll
    for (int off = 32; off > 0; off >>= 1) ss += __shfl_down(ss, off, 64);
    if (lane == 0) {
        sq[row]   = ss;
        rres[row] = idx[row] % MOD3;   // idx >= 0
    }
    if (row == 0 && lane < NLEV) { gsum[lane] = 0.f; gcnt[lane] = 0u; }
}

// ---------------------------------------------------------------------------
// Epilogue: DIAG specialization at block level. Invalid/over-cap pairs fold
// to v=6 (no bucket). Counts packed in u64 with 8-BIT fields (<=64/thread).
// ---------------------------------------------------------------------------
template<bool DIAG>
__device__ __forceinline__ void epilogue_acc(
    const f32x4 (&acc)[4][4], const float* sqI, const float* sqJ,
    const int* rI, const int* rJ, int I0, int J0, int wr, int wc, int lane,
    float (&lsum)[NLEV], u64& pcnt)
{
    const int rbase = (lane >> 4) * 4;   // C/D: row = (lane>>4)*4 + q, col = lane&15
    const int cbase = lane & 15;
#pragma unroll
    for (int m = 0; m < 4; ++m) {
        const int il0 = wr * 64 + m * 16 + rbase;
#pragma unroll
        for (int n = 0; n < 4; ++n) {
            const int jl  = wc * 64 + n * 16 + cbase;
            const float sqj = sqJ[jl];
            const int   rj  = rJ[jl];
#pragma unroll
            for (int q = 0; q < 4; ++q) {
                const int il = il0 + q;
                float d2 = fmaxf(sqI[il] + sqj - 2.0f * acc[m][n][q], 0.f);
                const float dist = __builtin_amdgcn_sqrtf(d2);   // v_sqrt_f32
                int dm = rI[il] - rj;
                dm += (dm >> 31) & MOD3;            // mod 729 into [0,729)
                const u32 x = (u32)dm;
                // v3 valuation capped at 6: 3^t | x <=> x*inv(3^t) <= thr_t
                int v =
                    (x * 2863311531u <= 1431655765u) +   // 3
                    (x *  954437177u <=  477218588u) +   // 9
                    (x * 1749801491u <=  159072862u) +   // 27
                    (x * 2014922929u <=   53024287u) +   // 81
                    (x * 3534952507u <=   17674762u) +   // 243
                    (x * 4041629033u <=    5891587u);    // 729 (x==0 -> 6)
                if (DIAG) {
                    v = ((J0 + jl) > (I0 + il)) ? v : 6;
                }
                float tv = 1.0f;
                tv = (v == 1) ? (1.f / 3.f)   : tv;
                tv = (v == 2) ? (1.f / 9.f)   : tv;
                tv = (v == 3) ? (1.f / 27.f)  : tv;
                tv = (v == 4) ? (1.f / 81.f)  : tv;
                tv = (v == 5) ? (1.f / 243.f) : tv;
                const float dd  = dist - tv;
                const float sqd = dd * dd;
#pragma unroll
                for (int vv = 0; vv < NLEV; ++vv)
                    lsum[vv] += (v == vv) ? sqd : 0.f;
                pcnt += 1ull << (8 * v);            // 8-bit field per class
            }
        }
    }
}

// ---------------------------------------------------------------------------
// Main: one block (256 thr = 4 waves, 2x2) per 128x128 tile pair (bi <= bj).
// Each wave owns a PRIVATE 64x64 quadrant computed entirely from registers:
// a/b fragments loaded straight from fragment-packed zpack (16 B/lane fully
// coalesced, L2-resident), 2-deep software pipeline, NO barriers in the
// k-loop. LDS only holds sq/rres (staged at entry, synced once after the
// k-loop). ~150 VGPR -> 3 blocks/CU: all 528 blocks co-resident, no tail.
// ---------------------------------------------------------------------------
__global__ __launch_bounds__(256, 3)
void pair_kernel(const u16* __restrict__ zpack, const float* __restrict__ sq,
                 const int* __restrict__ rres, float* __restrict__ gsum,
                 u32* __restrict__ gcnt)
{
    __shared__ float sqI[128], sqJ[128];
    __shared__ int   rI[128], rJ[128];
    __shared__ float bsum[NLEV];
    __shared__ u32   bcnt[NLEV];

    const int tid  = threadIdx.x;
    const int lane = tid & 63;
    const int wave = tid >> 6;

    // bijective XCD swizzle (528 = 8 * 66): consecutive wg on one XCD share
    // bi -> A-panel L2 locality.
    const int wg = (blockIdx.x & 7) * (NPAIR / 8) + (blockIdx.x >> 3);
    int t = wg, bi = 0, rem = NBLK;
    while (t >= rem) { t -= rem; ++bi; rem = NBLK - bi; }
    const int bj = bi + t;
    const int I0 = bi * 128, J0 = bj * 128;

    // stage sq/rres; no barrier needed until after the k-loop
    if (tid < 128)      { sqI[tid] = sq[I0 + tid]; rI[tid] = rres[I0 + tid]; }
    else                { int s = tid - 128; sqJ[s] = sq[J0 + s]; rJ[s] = rres[J0 + s]; }
    if (tid < NLEV) { bsum[tid] = 0.f; bcnt[tid] = 0u; }

    const int wr = wave >> 1, wc = wave & 1;     // 2x2 wave grid, 64x64 each
    const int RA = bi * 8 + wr * 4;              // A row-group base (16-row units)
    const int RB = bj * 8 + wc * 4;              // B row-group base

    f32x4 acc[4][4];
#pragma unroll
    for (int m = 0; m < 4; ++m)
#pragma unroll
        for (int n = 0; n < 4; ++n) acc[m][n] = (f32x4){0.f, 0.f, 0.f, 0.f};

    // frag (R, s) = zpack u16 index ((R*16 + s)*512) + lane*8
    const u16* zl = zpack + lane * 8;

#define LOADF(A, B, s)                                                         \
    {                                                                          \
        _Pragma("unroll")                                                      \
        for (int m = 0; m < 4; ++m) {                                          \
            A[m] = *reinterpret_cast<const bf16x8*>(                           \
                zl + ((size_t)(RA + m) * 16 + (s)) * 512);                     \
            B[m] = *reinterpret_cast<const bf16x8*>(                           \
                zl + ((size_t)(RB + m) * 16 + (s)) * 512);                     \
        }                                                                      \
    }
#define MFMA_ALL(A, B)                                                         \
    {                                                                          \
        _Pragma("unroll")                                                      \
        for (int m = 0; m < 4; ++m)                                            \
            _Pragma("unroll")                                                  \
            for (int n = 0; n < 4; ++n)                                        \
                acc[m][n] = __builtin_amdgcn_mfma_f32_16x16x32_bf16(           \
                    A[m], B[n], acc[m][n], 0, 0, 0);                           \
    }

    bf16x8 aX[4], bX[4], aY[4], bY[4];
    LOADF(aX, bX, 0);
#pragma unroll
    for (int s = 0; s < NKS; s += 2) {
        LOADF(aY, bY, s + 1);
        MFMA_ALL(aX, bX);
        if (s + 2 < NKS) LOADF(aX, bX, s + 2);
        MFMA_ALL(aY, bY);
    }
#undef LOADF
#undef MFMA_ALL

    __syncthreads();   // sq/rres staged long ago; bsum/bcnt init visible

    // ---- fused epilogue ----
    float lsum[NLEV] = {0.f, 0.f, 0.f, 0.f, 0.f, 0.f};
    u64 pcnt = 0ull;
    if (bi == bj) epilogue_acc<true >(acc, sqI, sqJ, rI, rJ, I0, J0, wr, wc, lane, lsum, pcnt);
    else          epilogue_acc<false>(acc, sqI, sqJ, rI, rJ, I0, J0, wr, wc, lane, lsum, pcnt);

    // wave shuffle reduce (extract 8-bit count fields BEFORE reducing), LDS,
    // then global atomics
#pragma unroll
    for (int vv = 0; vv < NLEV; ++vv) {
        float s = lsum[vv];
        u32   c = (u32)((pcnt >> (8 * vv)) & 255ull);
#pragma unroll
        for (int off = 32; off > 0; off >>= 1) {
            s += __shfl_xor(s, off, 64);
            c += __shfl_xor(c, off, 64);
        }
        if (lane == 0) { atomicAdd(&bsum[vv], s); atomicAdd(&bcnt[vv], c); }
    }
    __syncthreads();
    if (tid < NLEV) {
        atomicAdd(&gsum[tid], bsum[tid]);
        atomicAdd(&gcnt[tid], bcnt[tid]);
    }
}

// ---------------------------------------------------------------------------
__global__ void finalize_kernel(const float* __restrict__ gsum,
                                const u32* __restrict__ gcnt,
                                float* __restrict__ out)
{
    if (blockIdx.x == 0 && threadIdx.x == 0) {
        const float w[NLEV] = {1.f, 1.f / 2.f, 1.f / 3.f, 1.f / 4.f, 1.f / 5.f, 1.f / 6.f};
        float total = 0.f, lc = 0.f;
#pragma unroll
        for (int v = 0; v < NLEV; ++v) {
            const float cnt = (float)gcnt[v];
            const float mse = gsum[v] / fmaxf(cnt, 1.f);
            const bool  use = gcnt[v] >= 2u;
            total += use ? w[v] * mse : 0.f;
            lc    += use ? 1.f : 0.f;
        }
        out[0] = total / fmaxf(lc, 1.f);
    }
}

// ---------------------------------------------------------------------------
extern "C" void kernel_launch(void* const* d_in, const int* in_sizes, int n_in,
                              void* d_out, int out_size, void* d_ws, size_t ws_size,
                              hipStream_t stream)
{
    const float* z   = (const float*)d_in[0];
    const int*   idx = (const int*)d_in[1];
    char* ws = (char*)d_ws;
    u16*   zpk  = (u16*)(ws + WS_ZPK);
    float* sq   = (float*)(ws + WS_SQ);
    int*   rres = (int*)(ws + WS_R);
    float* gsum = (float*)(ws + WS_ACC);
    u32*   gcnt = (u32*)(ws + WS_ACC + NLEV * 4);
    float* out  = (float*)d_out;

    prep_kernel<<<N_ROWS, 64, 0, stream>>>(z, idx, zpk, sq, rres, gsum, gcnt);
    pair_kernel<<<NPAIR, 256, 0, stream>>>(zpk, sq, rres, gsum, gcnt);
    finalize_kernel<<<1, 64, 0, stream>>>(gsum, gcnt, out);
}